// Round 8
// baseline (78.295 us; speedup 1.0000x reference)
//
#include <hip/hip_runtime.h>
#include <hip/hip_cooperative_groups.h>

namespace cg = cooperative_groups;

#define BLOCK  256
#define IPT    8                  // i's per thread (independent acc chains)
#define ITILE  (BLOCK * IPT)      // 2048 i's per block
#define TJ     64                 // j-chunk per block
#define SUB    16                 // float2 register-staged sub-chunk
#define TSCALE 32.0f              // > max possible |1 - pj + pi| (~9)
#define NHB    16                 // histogram blocks (placed LAST in grid)
#define NBIN   20                 // targets in [0, 20)

// One cooperative dispatch:
//   blocks [0, npair)           : pair tiles  -> partials[] (plain stores)
//   blocks [npair, npair+NHB)   : ballot-popcount histogram -> hist[]
//   grid.sync()
//   block 0                     : reduce + analytic count + divide -> out
__global__ __launch_bounds__(BLOCK) void prl_coop(
    const float* __restrict__ pred, const int* __restrict__ targ,
    int n, int gx, int npair,
    float* __restrict__ partials, int* __restrict__ hist,
    float* __restrict__ out)
{
    __shared__ float2 sj[TJ];
    __shared__ float  wsum[BLOCK / 64];
    __shared__ double dsum[BLOCK / 64];
    __shared__ int    whist[BLOCK / 64][NBIN];

    const int tid  = threadIdx.x;
    const int bid  = blockIdx.x;
    const int wave = tid >> 6;
    const int lane = tid & 63;

    if (bid >= npair) {
        // ---------- ballot-popcount histogram block (no atomics) ----------
        const int hb = bid - npair;

        int c[NBIN];
        #pragma unroll
        for (int v = 0; v < NBIN; ++v) c[v] = 0;

        const int CHUNK = NHB * BLOCK * 2;            // 8192: one iter for n=8192
        const int iters = (n + CHUNK - 1) / CHUNK;
        for (int it = 0; it < iters; ++it) {
            const int i0 = it * CHUNK + hb * BLOCK * 2 + tid * 2;
            const int t0 = (i0     < n) ? targ[i0]     : -1;
            const int t1 = (i0 + 1 < n) ? targ[i0 + 1] : -1;
            #pragma unroll
            for (int v = 0; v < NBIN; ++v)
                c[v] += __popcll(__ballot(t0 == v)) + __popcll(__ballot(t1 == v));
        }

        if (lane == 0) {
            #pragma unroll
            for (int v = 0; v < NBIN; ++v) whist[wave][v] = c[v];
        }
        __syncthreads();
        if (tid < NBIN) {
            int h = 0;
            #pragma unroll
            for (int w = 0; w < BLOCK / 64; ++w) h += whist[w][tid];
            hist[hb * NBIN + tid] = h;                 // plain store
        }
    } else {
        // ---------- pair tile block ----------
        const int bx = bid % gx;
        const int by = bid / gx;
        const int i0 = bx * ITILE;
        const int j0 = by * TJ;

        float pi[IPT], Ei[IPT], s[IPT];
        #pragma unroll
        for (int m = 0; m < IPT; ++m) {
            const int i = i0 + m * BLOCK + tid;
            if (i < n) {
                const float p = pred[i];
                pi[m] = p;
                Ei[m] = __fmaf_rn(-TSCALE, (float)targ[i], p);     // p - 32*t
            } else {
                pi[m] = 0.0f; Ei[m] = -1.0e9f;                     // never contributes
            }
            s[m] = 0.0f;
        }

        if (tid < TJ) {
            const int j = j0 + tid;
            float q, F;
            if (j < n) {
                const float pj = pred[j];
                q = 1.0f - pj;
                F = __fmaf_rn(TSCALE, (float)targ[j], q - TSCALE); // q + 32*t - 32
            } else {
                q = 0.0f; F = -1.0e9f;                             // never contributes
            }
            sj[tid] = make_float2(q, F);
        }
        __syncthreads();

        #pragma unroll
        for (int sub = 0; sub < TJ / SUB; ++sub) {
            float2 r[SUB];
            #pragma unroll
            for (int k = 0; k < SUB; ++k) r[k] = sj[sub * SUB + k];  // batched ds_reads
            #pragma unroll
            for (int k = 0; k < SUB; ++k) {
                const float qk = r[k].x;
                const float Fk = r[k].y;
                #pragma unroll
                for (int m = 0; m < IPT; ++m) {
                    const float g = Ei[m] + Fk;        // x + 32*(tj-ti-1)
                    const float x = pi[m] + qk;        // 1 - (pj - pi)
                    s[m] += fmaxf(fminf(g, x), 0.0f);  // hinge iff ti < tj
                }
            }
        }

        float st = 0.0f;
        #pragma unroll
        for (int m = 0; m < IPT; ++m) st += s[m];
        #pragma unroll
        for (int off = 32; off; off >>= 1) st += __shfl_down(st, off);

        if (lane == 0) wsum[wave] = st;
        __syncthreads();
        if (tid == 0) {
            float b = 0.0f;
            #pragma unroll
            for (int w = 0; w < BLOCK / 64; ++w) b += wsum[w];
            partials[bid] = b;                         // plain store
        }
    }

    // ---------- grid-wide barrier (device-scope visibility) ----------
    cg::this_grid().sync();

    // ---------- finalize on block 0 ----------
    if (bid == 0) {
        double s = 0.0;
        for (int i = tid; i < npair; i += BLOCK) s += (double)partials[i];
        #pragma unroll
        for (int off = 32; off; off >>= 1) s += __shfl_down(s, off);
        if (lane == 0) dsum[wave] = s;

        __shared__ int hv[NBIN];
        if (tid < NBIN) {
            int h = 0;
            #pragma unroll
            for (int b = 0; b < NHB; ++b) h += hist[b * NBIN + tid];
            hv[tid] = h;
        }
        __syncthreads();

        if (tid == 0) {
            double tot = 0.0;
            #pragma unroll
            for (int w = 0; w < BLOCK / 64; ++w) tot += dsum[w];
            long long sq = 0;
            #pragma unroll
            for (int v = 0; v < NBIN; ++v) { const long long h = hv[v]; sq += h * h; }
            const long long cnt = ((long long)n * (long long)n - sq) / 2;  // #(t_i<t_j)
            out[0] = (cnt > 0) ? (float)(tot / (double)cnt) : 0.0f;
        }
    }
}

extern "C" void kernel_launch(void* const* d_in, const int* in_sizes, int n_in,
                              void* d_out, int out_size, void* d_ws, size_t ws_size,
                              hipStream_t stream) {
    const float* pred = (const float*)d_in[0];
    const int*   targ = (const int*)d_in[1];
    float*       out  = (float*)d_out;
    int          n    = in_sizes[0];

    int gx    = (n + ITILE - 1) / ITILE;   // 4   for n=8192
    int gy    = (n + TJ - 1) / TJ;         // 128
    int npair = gx * gy;                   // 512

    float* partials = (float*)d_ws;
    int*   hist     = (int*)((char*)d_ws + ((size_t)npair + 64) * sizeof(float));

    void* args[] = { (void*)&pred, (void*)&targ, (void*)&n, (void*)&gx,
                     (void*)&npair, (void*)&partials, (void*)&hist, (void*)&out };
    hipLaunchCooperativeKernel((const void*)prl_coop, dim3(npair + NHB), dim3(BLOCK),
                               args, 0, stream);
}

// Round 9
// 16.864 us; speedup vs baseline: 4.6427x; 4.6427x over previous
//
#include <hip/hip_runtime.h>

#define BLOCK  256
#define IPT    8                  // i's per thread (independent acc chains)
#define ITILE  (BLOCK * IPT)      // 2048 i's per block
#define TJ     64                 // j-chunk per block
#define TSCALE 32.0f              // > max possible |1 - pj + pi| (~9)
#define NHB    16                 // histogram blocks (placed last in grid)
#define NBIN   20                 // targets in [0, 20)

typedef float vf2 __attribute__((ext_vector_type(2)));
typedef float vf4 __attribute__((ext_vector_type(4)));

// kernel 1: blocks [0,npair) pair tiles; blocks [npair, npair+NHB) histogram.
// All outputs plain stores -> no memset / atomics anywhere.
__global__ __launch_bounds__(BLOCK) void prl_main(
    const float* __restrict__ pred, const int* __restrict__ targ,
    int n, int gx, int npair,
    float* __restrict__ partials,     // [npair]
    int*   __restrict__ hist)         // [NHB * NBIN]
{
    const int tid = threadIdx.x;

    if ((int)blockIdx.x >= npair) {
        // ---------- ballot-popcount histogram block (no atomics) ----------
        const int hb   = blockIdx.x - npair;
        const int wave = tid >> 6;
        const int lane = tid & 63;

        int c[NBIN];
        #pragma unroll
        for (int v = 0; v < NBIN; ++v) c[v] = 0;

        const int CHUNK = NHB * BLOCK * 2;            // 8192: one iter for n=8192
        const int iters = (n + CHUNK - 1) / CHUNK;
        for (int it = 0; it < iters; ++it) {
            const int i0 = it * CHUNK + hb * BLOCK * 2 + tid * 2;
            const int t0 = (i0     < n) ? targ[i0]     : -1;
            const int t1 = (i0 + 1 < n) ? targ[i0 + 1] : -1;
            #pragma unroll
            for (int v = 0; v < NBIN; ++v)
                c[v] += __popcll(__ballot(t0 == v)) + __popcll(__ballot(t1 == v));
        }

        __shared__ int whist[BLOCK / 64][NBIN];
        if (lane == 0) {
            #pragma unroll
            for (int v = 0; v < NBIN; ++v) whist[wave][v] = c[v];
        }
        __syncthreads();
        if (tid < NBIN) {
            int h = 0;
            #pragma unroll
            for (int w = 0; w < BLOCK / 64; ++w) h += whist[w][tid];
            hist[hb * NBIN + tid] = h;                 // plain store
        }
    } else {
        // ---------- pair tile block (packed 2-at-a-time inner loop) ----------
        __shared__ float sq[TJ];             // q = 1 - pj
        __shared__ float sF[TJ];             // F = q + 32*tj - 32
        __shared__ float wsum[BLOCK / 64];

        const int bx = blockIdx.x % gx;
        const int by = blockIdx.x / gx;
        const int i0 = bx * ITILE;
        const int j0 = by * TJ;

        vf2 pi2[IPT], Ei2[IPT], s2[IPT];
        #pragma unroll
        for (int m = 0; m < IPT; ++m) {
            const int i = i0 + m * BLOCK + tid;
            float p, E;
            if (i < n) {
                p = pred[i];
                E = __fmaf_rn(-TSCALE, (float)targ[i], p);     // p - 32*t
            } else {
                p = 0.0f; E = -1.0e9f;                         // never contributes
            }
            pi2[m] = (vf2){p, p};
            Ei2[m] = (vf2){E, E};
            s2[m]  = (vf2){0.0f, 0.0f};
        }

        if (tid < TJ) {
            const int j = j0 + tid;
            float q, F;
            if (j < n) {
                const float pj = pred[j];
                q = 1.0f - pj;
                F = __fmaf_rn(TSCALE, (float)targ[j], q - TSCALE); // q + 32*t - 32
            } else {
                q = 0.0f; F = -1.0e9f;                             // never contributes
            }
            sq[tid] = q;
            sF[tid] = F;
        }
        __syncthreads();

        #pragma unroll
        for (int sub = 0; sub < TJ / 16; ++sub) {
            // stage 16 j's: 4 float4 of q, 4 float4 of F (ds_read_b128)
            vf4 rq[4], rF[4];
            #pragma unroll
            for (int k = 0; k < 4; ++k) {
                rq[k] = ((const vf4*)sq)[sub * 4 + k];
                rF[k] = ((const vf4*)sF)[sub * 4 + k];
            }
            #pragma unroll
            for (int k = 0; k < 4; ++k) {
                const vf2 qlo = __builtin_shufflevector(rq[k], rq[k], 0, 1);
                const vf2 qhi = __builtin_shufflevector(rq[k], rq[k], 2, 3);
                const vf2 Flo = __builtin_shufflevector(rF[k], rF[k], 0, 1);
                const vf2 Fhi = __builtin_shufflevector(rF[k], rF[k], 2, 3);
                #pragma unroll
                for (int m = 0; m < IPT; ++m) {
                    vf2 g = Ei2[m] + Flo;              // v_pk_add_f32
                    vf2 x = pi2[m] + qlo;              // v_pk_add_f32
                    vf2 h;
                    h[0] = fmaxf(fminf(g[0], x[0]), 0.0f);
                    h[1] = fmaxf(fminf(g[1], x[1]), 0.0f);
                    s2[m] += h;                        // v_pk_add_f32
                }
                #pragma unroll
                for (int m = 0; m < IPT; ++m) {
                    vf2 g = Ei2[m] + Fhi;
                    vf2 x = pi2[m] + qhi;
                    vf2 h;
                    h[0] = fmaxf(fminf(g[0], x[0]), 0.0f);
                    h[1] = fmaxf(fminf(g[1], x[1]), 0.0f);
                    s2[m] += h;
                }
            }
        }

        float st = 0.0f;
        #pragma unroll
        for (int m = 0; m < IPT; ++m) st += s2[m][0] + s2[m][1];
        #pragma unroll
        for (int off = 32; off; off >>= 1) st += __shfl_down(st, off);

        const int wave = tid >> 6;
        if ((tid & 63) == 0) wsum[wave] = st;
        __syncthreads();
        if (tid == 0) {
            float b = 0.0f;
            #pragma unroll
            for (int w = 0; w < BLOCK / 64; ++w) b += wsum[w];
            partials[blockIdx.x] = b;                  // plain store
        }
    }
}

// kernel 2: tiny reduce + analytic count + divide.
__global__ __launch_bounds__(BLOCK) void prl_final(
    const float* __restrict__ partials, int npair,
    const int* __restrict__ hist, int n, float* __restrict__ out)
{
    __shared__ double wsum[BLOCK / 64];
    __shared__ int    hv[NBIN];
    const int tid = threadIdx.x;

    double s = 0.0;
    for (int i = tid; i < npair; i += BLOCK) s += (double)partials[i];
    #pragma unroll
    for (int off = 32; off; off >>= 1) s += __shfl_down(s, off);
    if ((tid & 63) == 0) wsum[tid >> 6] = s;

    if (tid < NBIN) {
        int h = 0;
        #pragma unroll
        for (int b = 0; b < NHB; ++b) h += hist[b * NBIN + tid];
        hv[tid] = h;
    }
    __syncthreads();

    if (tid == 0) {
        double tot = 0.0;
        #pragma unroll
        for (int w = 0; w < BLOCK / 64; ++w) tot += wsum[w];
        long long sq = 0;
        #pragma unroll
        for (int v = 0; v < NBIN; ++v) { const long long h = hv[v]; sq += h * h; }
        const long long cnt = ((long long)n * (long long)n - sq) / 2;  // #(t_i<t_j)
        out[0] = (cnt > 0) ? (float)(tot / (double)cnt) : 0.0f;
    }
}

extern "C" void kernel_launch(void* const* d_in, const int* in_sizes, int n_in,
                              void* d_out, int out_size, void* d_ws, size_t ws_size,
                              hipStream_t stream) {
    const float* pred = (const float*)d_in[0];
    const int*   targ = (const int*)d_in[1];
    float*       out  = (float*)d_out;
    const int    n    = in_sizes[0];

    const int gx    = (n + ITILE - 1) / ITILE;   // 4   for n=8192
    const int gy    = (n + TJ - 1) / TJ;         // 128
    const int npair = gx * gy;                   // 512

    float* partials = (float*)d_ws;
    int*   hist     = (int*)((char*)d_ws + ((size_t)npair + 64) * sizeof(float));

    prl_main<<<npair + NHB, BLOCK, 0, stream>>>(pred, targ, n, gx, npair, partials, hist);
    prl_final<<<1, BLOCK, 0, stream>>>(partials, npair, hist, n, out);
}